// Round 1
// baseline (3266.708 us; speedup 1.0000x reference)
//
#include <hip/hip_runtime.h>

#define T 252
#define TPAD 253
#define NLVL 4
#define NOUT 500
#define NSEL 20
#define UBV 0.1f

// ws layout (floats):
//   [0)        wT1  : conv1 weights [L][i][k][c]   49152
//   [49152)    wT2  : conv2 weights [L][i][k][c]   49152
//   [98304)    awT  : attn_w^T [c][a]              32000
//   [130304)   fwT  : fc_w^T   [c][a]              32000
//   [162304)   pooled [B][64]                      131072
#define OFF_WT2    49152
#define OFF_AWT    98304
#define OFF_FWT    130304
#define OFF_POOLED 162304

__global__ __launch_bounds__(256) void transpose_kernel(
    const float* __restrict__ w1, const float* __restrict__ w2,
    const float* __restrict__ aw, const float* __restrict__ fw,
    float* __restrict__ ws)
{
    int idx = blockIdx.x * 256 + threadIdx.x;
    if (idx < 49152) {
        // src: [l][c][i][k]  (l*12288 + c*192 + i*3 + k)
        int l = idx / 12288, r = idx - l * 12288;
        int c = r / 192,     r2 = r - c * 192;
        int i = r2 / 3,      k = r2 - i * 3;
        int dst = l * 12288 + (i * 3 + k) * 64 + c;
        ws[dst]           = w1[idx];
        ws[OFF_WT2 + dst] = w2[idx];
    }
    if (idx < 32000) {
        int a = idx >> 6, c = idx & 63;   // src [a][c]
        ws[OFF_AWT + c * 500 + a] = aw[idx];
        ws[OFF_FWT + c * 500 + a] = fw[idx];
    }
}

__global__ __launch_bounds__(256, 2) void conv_kernel(
    const float* __restrict__ x,
    const float* __restrict__ ws,
    const float* __restrict__ b1,
    const float* __restrict__ b2,
    float* __restrict__ pooled)
{
    __shared__ float hs[64 * TPAD];   // 64768 B

    const int b   = blockIdx.x;
    const int tid = threadIdx.x;

    // load + transpose x[b] : [T][64] -> hs[f][t]
    const float4* xb = (const float4*)(x + (size_t)b * (T * 64));
    for (int v = tid; v < T * 16; v += 256) {
        float4 val = xb[v];
        int t = v >> 4, f = (v & 15) << 2;
        hs[(f + 0) * TPAD + t] = val.x;
        hs[(f + 1) * TPAD + t] = val.y;
        hs[(f + 2) * TPAD + t] = val.z;
        hs[(f + 3) * TPAD + t] = val.w;
    }
    __syncthreads();

    const int  t      = tid;
    const bool active = (t < T);
    const int  te     = active ? t : (T - 1);

    float acc[64], hcol[64];

    for (int lvl = 0; lvl < NLVL; ++lvl) {
        const int d = 1 << lvl;
        const float* W1 = ws + lvl * 12288;
        const float* W2 = ws + OFF_WT2 + lvl * 12288;
        const float* B1 = b1 + lvl * 64;
        const float* B2 = b2 + lvl * 64;

        // ---- conv1: o1 = relu(W1 * h + b1) ----
        #pragma unroll
        for (int c = 0; c < 64; ++c) acc[c] = B1[c];
        #pragma unroll 2
        for (int i = 0; i < 64; ++i) {
            const float* hr = hs + i * TPAD + te;
            float h2 = hr[0];
            float h1 = (t >= d)     ? hr[-d]     : 0.f;
            float h0 = (t >= 2 * d) ? hr[-2 * d] : 0.f;
            const float* Wi = W1 + i * 192;    // [k][c], k=0 pairs h[t-2d]
            #pragma unroll
            for (int c = 0; c < 64; ++c) {
                float a = acc[c];
                a = fmaf(Wi[c],       h0, a);
                a = fmaf(Wi[64 + c],  h1, a);
                a = fmaf(Wi[128 + c], h2, a);
                acc[c] = a;
            }
        }
        // residual column (read BEFORE overwriting h with o1)
        #pragma unroll
        for (int c = 0; c < 64; ++c) hcol[c] = hs[c * TPAD + te];
        __syncthreads();
        if (active) {
            #pragma unroll
            for (int c = 0; c < 64; ++c) hs[c * TPAD + t] = fmaxf(acc[c], 0.f);
        }
        __syncthreads();

        // ---- conv2 + residual: h = relu(relu(W2 * o1 + b2) + h) ----
        #pragma unroll
        for (int c = 0; c < 64; ++c) acc[c] = B2[c];
        #pragma unroll 2
        for (int i = 0; i < 64; ++i) {
            const float* hr = hs + i * TPAD + te;
            float h2 = hr[0];
            float h1 = (t >= d)     ? hr[-d]     : 0.f;
            float h0 = (t >= 2 * d) ? hr[-2 * d] : 0.f;
            const float* Wi = W2 + i * 192;
            #pragma unroll
            for (int c = 0; c < 64; ++c) {
                float a = acc[c];
                a = fmaf(Wi[c],       h0, a);
                a = fmaf(Wi[64 + c],  h1, a);
                a = fmaf(Wi[128 + c], h2, a);
                acc[c] = a;
            }
        }
        __syncthreads();
        if (active) {
            #pragma unroll
            for (int c = 0; c < 64; ++c)
                hs[c * TPAD + t] = fmaxf(fmaxf(acc[c], 0.f) + hcol[c], 0.f);
        }
        __syncthreads();
    }

    // ---- max-pool over time ----
    {
        int c = tid & 63, part = tid >> 6;
        const float* row = hs + c * TPAD + part * 63;
        float m = row[0];
        for (int j = 1; j < 63; ++j) m = fmaxf(m, row[j]);
        __syncthreads();
        hs[tid] = m;     // safe: all reads of hs rows completed
        __syncthreads();
        if (tid < 64) {
            float mm = fmaxf(fmaxf(hs[tid], hs[tid + 64]),
                             fmaxf(hs[tid + 128], hs[tid + 192]));
            pooled[(size_t)b * 64 + tid] = mm;
        }
    }
}

__global__ __launch_bounds__(256) void head_kernel(
    const float* __restrict__ ws,
    const float* __restrict__ proj_w,
    const float* __restrict__ proj_b,
    const float* __restrict__ attn_b,
    const float* __restrict__ fc_b,
    float* __restrict__ out)
{
    const float* awT    = ws + OFF_AWT;
    const float* fwT    = ws + OFF_FWT;
    const float* pooled = ws + OFF_POOLED;

    __shared__ float z[64];
    __shared__ float rs[8];
    __shared__ unsigned long long ks[4];

    const int b   = blockIdx.x;
    const int tid = threadIdx.x;
    const int wv  = tid >> 6, ln = tid & 63;

    // z = relu(pooled @ proj_w^T + proj_b)
    if (tid < 64) {
        float s = proj_b[tid];
        const float* pw = proj_w + tid * 64;
        const float* pl = pooled + (size_t)b * 64;
        #pragma unroll 8
        for (int c = 0; c < 64; ++c) s = fmaf(pw[c], pl[c], s);
        z[tid] = fmaxf(s, 0.f);
    }
    __syncthreads();

    const int a0  = tid;
    const int a1  = tid + 256;
    const int a1e = (a1 < NOUT) ? a1 : (NOUT - 1);

    // attn = sigmoid(z @ attn_w^T + attn_b)
    float l0 = attn_b[a0], l1 = attn_b[a1e];
    #pragma unroll 8
    for (int c = 0; c < 64; ++c) {
        float zc = z[c];
        l0 = fmaf(zc, awT[c * 500 + a0],  l0);
        l1 = fmaf(zc, awT[c * 500 + a1e], l1);
    }
    float v0 = 1.f / (1.f + expf(-l0));
    float v1 = (a1 < NOUT) ? 1.f / (1.f + expf(-l1)) : 0.f;   // sigmoid > 0 for valid

    // top-20 (ties -> lower index, matching lax.top_k)
    bool m0 = false, m1 = false;
    for (int s = 0; s < NSEL; ++s) {
        unsigned long long k0 = ((unsigned long long)__float_as_uint(v0) << 32)
                              | (unsigned)(0xFFFFFFFFu - (unsigned)a0);
        unsigned long long k1 = ((unsigned long long)__float_as_uint(v1) << 32)
                              | (unsigned)(0xFFFFFFFFu - (unsigned)a1);
        unsigned long long k = (k0 > k1) ? k0 : k1;
        for (int o = 32; o > 0; o >>= 1) {
            unsigned long long other = __shfl_xor(k, o);
            if (other > k) k = other;
        }
        if (ln == 0) ks[wv] = k;
        __syncthreads();
        unsigned long long kk = ks[0];
        if (ks[1] > kk) kk = ks[1];
        if (ks[2] > kk) kk = ks[2];
        if (ks[3] > kk) kk = ks[3];
        int wa = (int)(0xFFFFFFFFu - (unsigned)(kk & 0xFFFFFFFFu));
        if (wa == a0) { m0 = true; v0 = 0.f; }
        if (wa == a1) { m1 = true; v1 = 0.f; }
        __syncthreads();
    }

    // fc logits
    float f0 = fc_b[a0], f1 = fc_b[a1e];
    #pragma unroll 8
    for (int c = 0; c < 64; ++c) {
        float zc = z[c];
        f0 = fmaf(zc, fwT[c * 500 + a0],  f0);
        f1 = fmaf(zc, fwT[c * 500 + a1e], f1);
    }
    if (a1 >= NOUT) f1 = -1e30f;

    // softmax over all 500
    float mx = fmaxf(f0, f1);
    for (int o = 32; o > 0; o >>= 1) mx = fmaxf(mx, __shfl_xor(mx, o));
    if (ln == 0) rs[wv] = mx;
    __syncthreads();
    mx = fmaxf(fmaxf(rs[0], rs[1]), fmaxf(rs[2], rs[3]));
    __syncthreads();

    float e0 = expf(f0 - mx);
    float e1 = (a1 < NOUT) ? expf(f1 - mx) : 0.f;
    float sm = e0 + e1;
    for (int o = 32; o > 0; o >>= 1) sm += __shfl_xor(sm, o);
    if (ln == 0) rs[wv] = sm;
    __syncthreads();
    float Z = rs[0] + rs[1] + rs[2] + rs[3];
    __syncthreads();

    float p0 = m0 ? (e0 / Z) : 0.f;
    float p1 = m1 ? (e1 / Z) : 0.f;
    float S = p0 + p1;
    for (int o = 32; o > 0; o >>= 1) S += __shfl_xor(S, o);
    if (ln == 0) rs[wv] = S;
    __syncthreads();
    S = rs[0] + rs[1] + rs[2] + rs[3];
    __syncthreads();

    float w0 = p0 / (S + 1e-8f);
    float w1 = p1 / (S + 1e-8f);

    // water-filling rebalance: 1 + 16 iterations; gated iterations are exact
    // fixed points (leftover == 0.0 -> update adds exactly 0), so run all 17.
    for (int it = 0; it < 17; ++it) {
        float c0 = fminf(fmaxf(w0, 0.f), UBV);
        float c1 = fminf(fmaxf(w1, 0.f), UBV);
        float lo = (w0 - c0) + (w1 - c1);
        float ns = ((c0 != UBV) ? c0 : 0.f) + ((c1 != UBV) ? c1 : 0.f);
        for (int o = 32; o > 0; o >>= 1) {
            lo += __shfl_xor(lo, o);
            ns += __shfl_xor(ns, o);
        }
        if (ln == 0) { rs[wv * 2] = lo; rs[wv * 2 + 1] = ns; }
        __syncthreads();
        lo = rs[0] + rs[2] + rs[4] + rs[6];
        ns = rs[1] + rs[3] + rs[5] + rs[7];
        __syncthreads();
        if (ns == 0.f) ns = 1.f;
        w0 = (c0 != UBV) ? c0 + lo * c0 / ns : c0;
        w1 = (c1 != UBV) ? c1 + lo * c1 / ns : c1;
    }

    out[(size_t)b * 500 + a0] = w0;
    if (a1 < NOUT) out[(size_t)b * 500 + a1] = w1;
}

extern "C" void kernel_launch(void* const* d_in, const int* in_sizes, int n_in,
                              void* d_out, int out_size, void* d_ws, size_t ws_size,
                              hipStream_t stream)
{
    const float* x   = (const float*)d_in[0];
    const float* c1w = (const float*)d_in[1];
    const float* c1b = (const float*)d_in[2];
    const float* c2w = (const float*)d_in[3];
    const float* c2b = (const float*)d_in[4];
    const float* pw  = (const float*)d_in[5];
    const float* pb  = (const float*)d_in[6];
    const float* aw  = (const float*)d_in[7];
    const float* ab  = (const float*)d_in[8];
    const float* fw  = (const float*)d_in[9];
    const float* fb  = (const float*)d_in[10];

    float* ws  = (float*)d_ws;
    float* out = (float*)d_out;

    transpose_kernel<<<192, 256, 0, stream>>>(c1w, c2w, aw, fw, ws);
    conv_kernel<<<2048, 256, 0, stream>>>(x, ws, c1b, c2b, ws + OFF_POOLED);
    head_kernel<<<2048, 256, 0, stream>>>(ws, pw, pb, ab, fb, out);
}